// Round 1
// 2111.345 us; speedup vs baseline: 1.1452x; 1.1452x over previous
//
#include <hip/hip_runtime.h>
#include <hip/hip_bf16.h>
#include <math.h>

#define T_TOK 4096
#define H_DIM 2048
#define I_DIM 8192
#define N_EXP 8

typedef short bf16x8 __attribute__((ext_vector_type(8)));
typedef float f32x4 __attribute__((ext_vector_type(4)));

__device__ __forceinline__ ushort f2bf(float f) {
    union { float f; unsigned u; } v; v.f = f;
    unsigned u = v.u + 0x7fffu + ((v.u >> 16) & 1u);  // RNE
    return (ushort)(u >> 16);
}

__device__ __forceinline__ void gload16(const void* g, void* l) {
    __builtin_amdgcn_global_load_lds(
        (const __attribute__((address_space(1))) unsigned*)g,
        (__attribute__((address_space(3))) unsigned*)l, 16, 0, 0);
}

// ---------------- init: out = bias, zero counters ----------------
__global__ void k_init(float* __restrict__ out, const float* __restrict__ bias,
                       int* __restrict__ cnts) {
    int gid = blockIdx.x * 256 + threadIdx.x;
    size_t i = (size_t)gid * 4;
    if (i < (size_t)T_TOK * H_DIM) {
        float4 b = *(const float4*)&bias[i & (H_DIM - 1)];
        *(float4*)&out[i] = b;
    }
    if (gid < 16) cnts[gid] = 0;
}

// ---------------- x -> bf16 ----------------
__global__ void k_cvt_x(const float* __restrict__ x, ushort* __restrict__ xb) {
    size_t i = ((size_t)blockIdx.x * 256 + threadIdx.x) * 4;
    float4 v = *(const float4*)&x[i];
    ushort4 o;
    o.x = f2bf(v.x); o.y = f2bf(v.y); o.z = f2bf(v.z); o.w = f2bf(v.w);
    *(ushort4*)&xb[i] = o;
}

// ---------------- router: logits, top-2, weights, histogram ----------------
__global__ void k_router(const float* __restrict__ x, const float* __restrict__ gw,
                         float* __restrict__ logits, int* __restrict__ sel,
                         float* __restrict__ wts, int* __restrict__ cnt) {
    int t = blockIdx.x;
    int lane = threadIdx.x;
    const float* xr = x + (size_t)t * H_DIM;
    float s[8] = {0, 0, 0, 0, 0, 0, 0, 0};
    for (int h = lane; h < H_DIM; h += 64) {
        float xv = xr[h];
        const float* g = gw + h * 8;
        float4 g0 = *(const float4*)g;
        float4 g1 = *(const float4*)(g + 4);
        s[0] += xv * g0.x; s[1] += xv * g0.y; s[2] += xv * g0.z; s[3] += xv * g0.w;
        s[4] += xv * g1.x; s[5] += xv * g1.y; s[6] += xv * g1.z; s[7] += xv * g1.w;
    }
#pragma unroll
    for (int off = 32; off > 0; off >>= 1) {
#pragma unroll
        for (int e = 0; e < 8; e++) s[e] += __shfl_xor(s[e], off);
    }
    if (lane < 8) logits[t * 8 + lane] = s[lane];
    if (lane == 0) {
        int e0 = 0; float l0 = s[0];
        for (int e = 1; e < 8; e++) if (s[e] > l0) { l0 = s[e]; e0 = e; }
        int e1 = -1; float l1 = -3.0e38f;
        for (int e = 0; e < 8; e++) if (e != e0 && s[e] > l1) { l1 = s[e]; e1 = e; }
        float w0 = 1.0f / (1.0f + expf(l1 - l0));  // softmax over {l0,l1}
        float w1 = 1.0f - w0;
        sel[t * 2] = e0; sel[t * 2 + 1] = e1;
        wts[t * 2] = w0; wts[t * 2 + 1] = w1;
        atomicAdd(&cnt[e0], 1);
        atomicAdd(&cnt[e1], 1);
    }
}

// ---------------- prefix sum over 8 counts ----------------
__global__ void k_prefix(const int* __restrict__ cnt, int* __restrict__ offs) {
    if (threadIdx.x == 0 && blockIdx.x == 0) {
        int a = 0;
        for (int e = 0; e < N_EXP; e++) { offs[e] = a; a += cnt[e]; }
        offs[N_EXP] = a;
    }
}

// ---------------- assign pair -> row ----------------
__global__ void k_assign(const int* __restrict__ sel, const float* __restrict__ wts,
                         const int* __restrict__ offs, int* __restrict__ cursor,
                         int* __restrict__ rowinfo, float* __restrict__ rowwt) {
    int t = blockIdx.x * 256 + threadIdx.x;
    if (t >= T_TOK) return;
#pragma unroll
    for (int k = 0; k < 2; k++) {
        int e = sel[t * 2 + k];
        int pos = atomicAdd(&cursor[e], 1);
        int row = offs[e] + pos;
        rowinfo[row] = t;
        rowwt[row] = wts[t * 2 + k];
    }
}

// ---------------- transpose + convert: fp32 [R][C] -> bf16 [C][R], per expert ----
template <int R, int C>
__global__ __launch_bounds__(256) void k_transcvt(const float* __restrict__ in,
                                                  ushort* __restrict__ outp) {
    const float* src = in + (size_t)blockIdx.z * R * C;
    ushort* dst = outp + (size_t)blockIdx.z * R * C;
    const int c0 = blockIdx.x * 64, r0 = blockIdx.y * 64;
    __shared__ float tile[64][65];
    const int t = threadIdx.x;
    const int tc = (t & 15) * 4;
    const int tr = t >> 4;
#pragma unroll
    for (int i = 0; i < 4; i++) {
        int r = tr + i * 16;
        float4 v = *(const float4*)&src[(size_t)(r0 + r) * C + c0 + tc];
        tile[r][tc] = v.x; tile[r][tc + 1] = v.y;
        tile[r][tc + 2] = v.z; tile[r][tc + 3] = v.w;
    }
    __syncthreads();
    const int oc = t >> 2;          // output row within tile (a column of src)
    const int ob = (t & 3) * 16;    // 16 output elements
    uint4 w0, w1;
    w0.x = (uint)f2bf(tile[ob + 0][oc]) | ((uint)f2bf(tile[ob + 1][oc]) << 16);
    w0.y = (uint)f2bf(tile[ob + 2][oc]) | ((uint)f2bf(tile[ob + 3][oc]) << 16);
    w0.z = (uint)f2bf(tile[ob + 4][oc]) | ((uint)f2bf(tile[ob + 5][oc]) << 16);
    w0.w = (uint)f2bf(tile[ob + 6][oc]) | ((uint)f2bf(tile[ob + 7][oc]) << 16);
    w1.x = (uint)f2bf(tile[ob + 8][oc]) | ((uint)f2bf(tile[ob + 9][oc]) << 16);
    w1.y = (uint)f2bf(tile[ob + 10][oc]) | ((uint)f2bf(tile[ob + 11][oc]) << 16);
    w1.z = (uint)f2bf(tile[ob + 12][oc]) | ((uint)f2bf(tile[ob + 13][oc]) << 16);
    w1.w = (uint)f2bf(tile[ob + 14][oc]) | ((uint)f2bf(tile[ob + 15][oc]) << 16);
    ushort* drow = dst + (size_t)(c0 + oc) * R + r0 + ob;
    *(uint4*)drow = w0;
    *(uint4*)(drow + 8) = w1;
}

// ---------------- MFMA GEMM: m97 structure, 128x128 tile, BK=32 ----------------
// A: bf16 rows (MODE 0: gathered via rowinfo from xb; MODE 1: direct hmid rows)
// B: pre-transposed bf16 [NDIM][KDIM] per expert
// LDS: linear [128][32] bf16 per operand, filled by global_load_lds (16B),
//      XOR-swizzled (bits 4-5 ^= row bits 1-2) on BOTH source k-offset and read.
template <int KDIM, int NDIM, int MODE>
__global__ __launch_bounds__(256) void k_gemm(
    const ushort* __restrict__ Abase, const ushort* __restrict__ BtBase,
    void* __restrict__ outp, const int* __restrict__ rowinfo,
    const float* __restrict__ rowwt, const int* __restrict__ offs) {
    const int e = blockIdx.z;
    const int row_start = offs[e], row_end = offs[e + 1];
    const int row0 = row_start + blockIdx.y * 128;
    if (row0 >= row_end) return;
    const int n0 = blockIdx.x * 128;
    const ushort* Bt = BtBase + (size_t)e * KDIM * NDIM;

    __shared__ ushort lds_a[128 * 32];
    __shared__ ushort lds_b[128 * 32];

    const int tid = threadIdx.x;
    const ushort* asrc[2];
    const ushort* bsrc[2];
    ushort* adst[2];
    ushort* bdst[2];
#pragma unroll
    for (int i = 0; i < 2; i++) {
        const int idx = tid + i * 256;           // 16B chunk index, 0..511
        const int r = idx >> 2;                  // tile row 0..127
        // swizzled k-offset (bytes): ((idx&3)<<4) ^ ((row>>1 & 3)<<4); row bits 1-2 == idx bits 3-4
        const int ke = ((((idx & 3) << 4) ^ (((idx >> 3) & 3) << 4)) >> 1);
        int rg = row0 + r;
        int rc = (rg < row_end) ? rg : row_start;  // clamp pad rows to a valid row
        if (MODE == 0) asrc[i] = Abase + (size_t)rowinfo[rc] * KDIM + ke;
        else           asrc[i] = Abase + (size_t)rc * KDIM + ke;
        bsrc[i] = Bt + (size_t)(n0 + r) * KDIM + ke;
        adst[i] = lds_a + (size_t)idx * 8;       // linear LDS dest (HW requirement)
        bdst[i] = lds_b + (size_t)idx * 8;
    }

    const int lane = tid & 63;
    const int wid = tid >> 6;
    const int wm = (wid & 1) * 64;
    const int wn = (wid >> 1) * 64;
    const int l15 = lane & 15;
    const int q16 = (lane >> 4) * 16;            // byte offset within row

    int aoff[4], boff[4];
#pragma unroll
    for (int mt = 0; mt < 4; mt++) {
        int r = wm + mt * 16 + l15;
        aoff[mt] = (r * 64 + q16) ^ (((r >> 1) & 3) << 4);
        r = wn + mt * 16 + l15;
        boff[mt] = (r * 64 + q16) ^ (((r >> 1) & 3) << 4);
    }

    f32x4 acc[4][4] = {};
    const char* lap = (const char*)lds_a;
    const char* lbp = (const char*)lds_b;

    for (int ks = 0; ks < KDIM / 32; ks++) {
#pragma unroll
        for (int i = 0; i < 2; i++) {
            gload16(asrc[i], adst[i]);
            gload16(bsrc[i], bdst[i]);
            asrc[i] += 32;
            bsrc[i] += 32;
        }
        __syncthreads();   // drains vmcnt: tiles staged; prev-iter readers already synced
        bf16x8 af[4], bfr[4];
#pragma unroll
        for (int mt = 0; mt < 4; mt++) af[mt] = *(const bf16x8*)(lap + aoff[mt]);
#pragma unroll
        for (int nt = 0; nt < 4; nt++) bfr[nt] = *(const bf16x8*)(lbp + boff[nt]);
#pragma unroll
        for (int mt = 0; mt < 4; mt++)
#pragma unroll
            for (int nt = 0; nt < 4; nt++)
                acc[mt][nt] = __builtin_amdgcn_mfma_f32_16x16x32_bf16(
                    af[mt], bfr[nt], acc[mt][nt], 0, 0, 0);
        __syncthreads();   // all waves done reading before next overwrite
    }

    const int qr = (lane >> 4) * 4;
#pragma unroll
    for (int mt = 0; mt < 4; mt++) {
#pragma unroll
        for (int rg = 0; rg < 4; rg++) {
            int rl = wm + mt * 16 + qr + rg;
            int rglob = row0 + rl;
            if (rglob < row_end) {
                if (MODE == 0) {
                    ushort* hm = (ushort*)outp + (size_t)rglob * NDIM + n0 + wn + l15;
#pragma unroll
                    for (int nt = 0; nt < 4; nt++) {
                        float v = acc[mt][nt][rg];
                        v = 0.5f * v * (1.0f + erff(v * 0.70710678118654752f));
                        hm[nt * 16] = f2bf(v);
                    }
                } else {
                    float w = rowwt[rglob];
                    int tok = rowinfo[rglob];
                    float* op = (float*)outp + (size_t)tok * NDIM + n0 + wn + l15;
#pragma unroll
                    for (int nt = 0; nt < 4; nt++)
                        atomicAdd(&op[nt * 16], w * acc[mt][nt][rg]);
                }
            }
        }
    }
}

// ---------------- launch ----------------
extern "C" void kernel_launch(void* const* d_in, const int* in_sizes, int n_in,
                              void* d_out, int out_size, void* d_ws, size_t ws_size,
                              hipStream_t stream) {
    const float* x     = (const float*)d_in[0];
    const float* gw    = (const float*)d_in[1];
    const float* w_in  = (const float*)d_in[2];
    const float* w_out = (const float*)d_in[3];
    const float* bias  = (const float*)d_in[4];

    float* out    = (float*)d_out;                       // [T*H]
    float* logits = out + (size_t)T_TOK * H_DIM;         // [T*8]

    char* ws = (char*)d_ws;
    // meta first (small), big buffers after
    int*    rowinfo = (int*)  (ws);                      // 32768 B
    float*  rowwt   = (float*)(ws + 32768);              // 32768 B
    int*    sel     = (int*)  (ws + 65536);              // 32768 B
    float*  wts     = (float*)(ws + 98304);              // 32768 B
    int*    cnt     = (int*)  (ws + 131072);             // 64 B (8 counts + 8 cursors)
    int*    offs    = (int*)  (ws + 131136);             // 64 B
    ushort* xb      = (ushort*)(ws + 262144);            // 16,777,216 B
    ushort* hmid    = (ushort*)(ws + 17039360);          // 134,217,728 B
    ushort* wt      = (ushort*)(ws + 151257088);         // 268,435,456 B (reused for both weights)
    const size_t WS_NEEDED = 419692544ull;
    if (ws_size < WS_NEEDED) return;  // fail loudly (stale output), never scribble OOB

    hipLaunchKernelGGL(k_init,   dim3(8192), dim3(256), 0, stream, out, bias, cnt);
    hipLaunchKernelGGL(k_cvt_x,  dim3(8192), dim3(256), 0, stream, x, xb);
    hipLaunchKernelGGL(k_router, dim3(4096), dim3(64),  0, stream, x, gw, logits, sel, wts, cnt);
    hipLaunchKernelGGL(k_prefix, dim3(1),    dim3(64),  0, stream, cnt, offs);
    hipLaunchKernelGGL(k_assign, dim3(16),   dim3(256), 0, stream, sel, wts, offs, cnt + 8, rowinfo, rowwt);

    // w_in [E][H][I] fp32 -> wt [E][I][H] bf16
    hipLaunchKernelGGL((k_transcvt<H_DIM, I_DIM>), dim3(I_DIM / 64, H_DIM / 64, 8), dim3(256),
                       0, stream, w_in, wt);
    hipLaunchKernelGGL((k_gemm<H_DIM, I_DIM, 0>), dim3(64, 32, 8), dim3(256), 0, stream,
                       xb, wt, (void*)hmid, rowinfo, rowwt, offs);

    // w_out [E][I][H] fp32 -> wt [E][H][I] bf16 (reuses wt; stream-serial after gemm1)
    hipLaunchKernelGGL((k_transcvt<I_DIM, H_DIM>), dim3(H_DIM / 64, I_DIM / 64, 8), dim3(256),
                       0, stream, w_out, wt);
    hipLaunchKernelGGL((k_gemm<I_DIM, H_DIM, 1>), dim3(16, 32, 8), dim3(256), 0, stream,
                       hmid, wt, (void*)out, rowinfo, rowwt, offs);
}